// Round 5
// baseline (353.629 us; speedup 1.0000x reference)
//
#include <hip/hip_runtime.h>
#include <hip/hip_bf16.h>

// ---------------------------------------------------------------------------
// MultiHeadAttention: x[2,2048,2048] f32, W_qkv[6144,2048], W_out[2048,2048]
// out = MHA(x) in fp32. Internally bf16 MFMA with fp32 accumulation.
// ---------------------------------------------------------------------------

typedef short bf16x8 __attribute__((ext_vector_type(8)));
typedef float f32x4  __attribute__((ext_vector_type(4)));

#define MFMA(a, b, c) __builtin_amdgcn_mfma_f32_16x16x32_bf16((a), (b), (c), 0, 0, 0)

#define GLDS16(gp, lp) __builtin_amdgcn_global_load_lds(                        \
    (const __attribute__((address_space(1))) void*)(gp),                        \
    (__attribute__((address_space(3))) void*)(lp), 16, 0, 0)

#define FENCE asm volatile("" ::: "memory")
#define BARRIER do { FENCE; __builtin_amdgcn_s_barrier(); FENCE; } while (0)

static __device__ __forceinline__ unsigned short f2bf(float f) {
    __hip_bfloat16 h = __float2bfloat16(f);
    return *reinterpret_cast<unsigned short*>(&h);
}

// ---------------- fp32 -> bf16 convert (vectorized) ------------------------
__global__ __launch_bounds__(256) void cvt_f32_bf16(const float* __restrict__ in,
                                                    unsigned short* __restrict__ out,
                                                    int n4) {
    int i = blockIdx.x * 256 + threadIdx.x;
    if (i < n4) {
        float4 v = reinterpret_cast<const float4*>(in)[i];
        ushort4 o;
        o.x = f2bf(v.x); o.y = f2bf(v.y); o.z = f2bf(v.z); o.w = f2bf(v.w);
        reinterpret_cast<ushort4*>(out)[i] = o;
    }
}

// ============================================================================
// 256x256 8-phase GEMM (T1+T2+T3+T4+T5): C[M,N] = A[M,K] * W[N,K]^T
// 8 waves (2M x 4N), per-wave 128x64. BK=64, 2 K-tiles/iteration, 8 phases.
// LDS 128 KiB: A/B tiles [256][64] bf16, double-buffered, st_16x32 swizzled.
// Staging: linear LDS dest + inverse-swizzled global source (rule #21).
// ds_read balance {6,6,4,8}/wave/phase (r4 was {12,4,8,0}: LDS-pipe-bound).
// ph4/ph8 pre-read NEXT tile's A-low-half after vmcnt(6)+barrier (landed).
// Staging/vmcnt schedule identical to r4 (verified in-flight accounting).
// ============================================================================

// region 0=A1 (quarters 0,2), 1=A2 (quarters 1,3), 2=B1 (sub 0-3 per quarter),
// 3=B2 (sub 4-7 per quarter). quarter=64 rows=8KB; subtile=16 rows x 32 cols.
template <int REGION>
__device__ __forceinline__ void stage_region(const unsigned short* __restrict__ G,
                                             int ld, int rc0, int kt, char* buf,
                                             int w, int lane) {
    const int srcRowOff = lane >> 2;
    const int srcColOff = ((lane & 3) * 8) ^ ((lane >> 5) << 4);  // elems (inv-swz)
#pragma unroll
    for (int j = 0; j < 2; ++j) {
        const int si = w * 2 + j;            // 0..15 subtiles per region
        int q, s;
        if (REGION < 2) { q = ((si >> 3) << 1) | REGION; s = si & 7; }
        else            { q = si >> 2; s = (si & 3) | ((REGION == 3) << 2); }
        const int rowBase = q * 64 + (s >> 1) * 16;
        const int colBase = (s & 1) * 32;
        const unsigned short* gp =
            G + (size_t)(rc0 + rowBase + srcRowOff) * ld + kt * 64 + colBase + srcColOff;
        GLDS16(gp, buf + (q << 13) + (s << 10));  // wave-uniform base, lane*16
    }
}

template <bool BF16OUT>
__global__ __launch_bounds__(512, 2) void gemm256(const unsigned short* __restrict__ A,
                                                  const unsigned short* __restrict__ W,
                                                  void* __restrict__ Cout,
                                                  int M, int N, int K) {
    __shared__ __align__(16) char As[2][32768];
    __shared__ __align__(16) char Bs[2][32768];
    const int tid = threadIdx.x;
    const int w = tid >> 6, lane = tid & 63;
    const int fr = lane & 15, fq = lane >> 4;
    const int wr = w >> 2, wc = w & 3;              // 2M x 4N waves
    const int nbx = N >> 8;
    const int cpx = gridDim.x >> 3;                 // grid % 8 == 0 by launch
    const int bid = blockIdx.x;
    const int swz = (bid & 7) * cpx + (bid >> 3);   // XCD-bijective (T1)
    const int n0 = (swz % nbx) << 8, m0 = (swz / nbx) << 8;
    // swizzled ds_read offset: inner = fr*64 + fq*16, ^32 when fr>=8
    const int laneoff = (fr * 64 + fq * 16) ^ ((fr >> 3) << 5);

#define LDA(bi, mi, kk) (*(const bf16x8*)(&As[bi][0] +                           \
    ((((wr << 1) | ((mi) >> 2)) << 13) | ((((mi) & 3) * 2 + (kk)) << 10)) + laneoff))
#define LDB(bi, ni, kk) (*(const bf16x8*)(&Bs[bi][0] +                           \
    ((wc << 13) | (((ni) * 2 + (kk)) << 10)) + laneoff))

    f32x4 acc[8][4];
#pragma unroll
    for (int mi = 0; mi < 8; ++mi)
#pragma unroll
        for (int ni = 0; ni < 4; ++ni) acc[mi][ni] = f32x4{0.f, 0.f, 0.f, 0.f};

    bf16x8 afA[4][2], afB[4][2], bfA[2][2], bfB[2][2];

    const int KT = K >> 6;                          // 64-wide K-tiles
    // Prologue: A1,B1,A2,B2(tile0) ; A1,B1,A2(tile1)  [7 regions = 14 loads]
    stage_region<0>(A, K, m0, 0, As[0], w, lane);
    stage_region<2>(W, K, n0, 0, Bs[0], w, lane);
    stage_region<1>(A, K, m0, 0, As[0], w, lane);
    stage_region<3>(W, K, n0, 0, Bs[0], w, lane);
    stage_region<0>(A, K, m0, 1, As[1], w, lane);
    stage_region<2>(W, K, n0, 1, Bs[1], w, lane);
    stage_region<1>(A, K, m0, 1, As[1], w, lane);
    asm volatile("s_waitcnt vmcnt(6)" ::: "memory");  // tile0 landed
    BARRIER;
    // pre-read A-low-half of tile0 (buf0)
#pragma unroll
    for (int mi = 0; mi < 4; ++mi) { afA[mi][0] = LDA(0, mi, 0); afA[mi][1] = LDA(0, mi, 1); }

#define MFMAQ(AF, BF, MIBASE, NIBASE)                                            \
    __builtin_amdgcn_s_setprio(1);                                               \
    _Pragma("unroll")                                                            \
    for (int mi = 0; mi < 4; ++mi)                                               \
    _Pragma("unroll")                                                            \
    for (int ni = 0; ni < 2; ++ni)                                               \
    _Pragma("unroll")                                                            \
    for (int kk = 0; kk < 2; ++kk)                                               \
        acc[(MIBASE) + mi][(NIBASE) + ni] =                                      \
            MFMA((AF)[mi][kk], (BF)[ni][kk], acc[(MIBASE) + mi][(NIBASE) + ni]); \
    __builtin_amdgcn_s_setprio(0)

    const int KT2 = KT >> 1;
    for (int it = 0; it < KT2; ++it) {
        const int t1 = 2 * it + 1;
        const int pfa = (2 * it + 2 < KT) ? 2 * it + 2 : KT - 2;  // even -> buf0
        const int pfb = (t1 + 2 < KT) ? t1 + 2 : KT - 1;          // odd  -> buf1
        // ---------------- tile 2it (buf 0) ----------------
        // ph1: rd bfA(4) + afB[0](2); stage B2(t1)->buf1
#pragma unroll
        for (int ni = 0; ni < 2; ++ni) { bfA[ni][0] = LDB(0, ni, 0); bfA[ni][1] = LDB(0, ni, 1); }
        afB[0][0] = LDA(0, 4, 0); afB[0][1] = LDA(0, 4, 1);
        stage_region<3>(W, K, n0, t1, Bs[1], w, lane);
        BARRIER;
        MFMAQ(afA, bfA, 0, 0);
        BARRIER;
        // ph2: rd bfB(4) + afB[1](2); stage A1(pfa)->buf0
#pragma unroll
        for (int ni = 0; ni < 2; ++ni) { bfB[ni][0] = LDB(0, ni + 2, 0); bfB[ni][1] = LDB(0, ni + 2, 1); }
        afB[1][0] = LDA(0, 5, 0); afB[1][1] = LDA(0, 5, 1);
        stage_region<0>(A, K, m0, pfa, As[0], w, lane);
        BARRIER;
        MFMAQ(afA, bfB, 0, 2);
        BARRIER;
        // ph3: rd afB[2,3](4); stage B1(pfa)->buf0
        afB[2][0] = LDA(0, 6, 0); afB[2][1] = LDA(0, 6, 1);
        afB[3][0] = LDA(0, 7, 0); afB[3][1] = LDA(0, 7, 1);
        stage_region<2>(W, K, n0, pfa, Bs[0], w, lane);
        BARRIER;
        MFMAQ(afB, bfA, 4, 0);
        BARRIER;
        // ph4: stage A2(pfa)->buf0; vmcnt(6) => tile t1 landed; pre-read afA(t1)
        stage_region<1>(A, K, m0, pfa, As[0], w, lane);
        asm volatile("s_waitcnt vmcnt(6)" ::: "memory");
        BARRIER;
#pragma unroll
        for (int mi = 0; mi < 4; ++mi) { afA[mi][0] = LDA(1, mi, 0); afA[mi][1] = LDA(1, mi, 1); }
        MFMAQ(afB, bfB, 4, 2);
        BARRIER;
        // ---------------- tile 2it+1 (buf 1) ----------------
        // ph5: rd bfA(4) + afB[0](2); stage B2(pfa)->buf0
#pragma unroll
        for (int ni = 0; ni < 2; ++ni) { bfA[ni][0] = LDB(1, ni, 0); bfA[ni][1] = LDB(1, ni, 1); }
        afB[0][0] = LDA(1, 4, 0); afB[0][1] = LDA(1, 4, 1);
        stage_region<3>(W, K, n0, pfa, Bs[0], w, lane);
        BARRIER;
        MFMAQ(afA, bfA, 0, 0);
        BARRIER;
        // ph6: rd bfB(4) + afB[1](2); stage A1(pfb)->buf1
#pragma unroll
        for (int ni = 0; ni < 2; ++ni) { bfB[ni][0] = LDB(1, ni + 2, 0); bfB[ni][1] = LDB(1, ni + 2, 1); }
        afB[1][0] = LDA(1, 5, 0); afB[1][1] = LDA(1, 5, 1);
        stage_region<0>(A, K, m0, pfb, As[1], w, lane);
        BARRIER;
        MFMAQ(afA, bfB, 0, 2);
        BARRIER;
        // ph7: rd afB[2,3](4); stage B1(pfb)->buf1
        afB[2][0] = LDA(1, 6, 0); afB[2][1] = LDA(1, 6, 1);
        afB[3][0] = LDA(1, 7, 0); afB[3][1] = LDA(1, 7, 1);
        stage_region<2>(W, K, n0, pfb, Bs[1], w, lane);
        BARRIER;
        MFMAQ(afB, bfA, 4, 0);
        BARRIER;
        // ph8: stage A2(pfb)->buf1; vmcnt(6) => tile pfa landed; pre-read afA(pfa)
        stage_region<1>(A, K, m0, pfb, As[1], w, lane);
        asm volatile("s_waitcnt vmcnt(6)" ::: "memory");
        BARRIER;
#pragma unroll
        for (int mi = 0; mi < 4; ++mi) { afA[mi][0] = LDA(0, mi, 0); afA[mi][1] = LDA(0, mi, 1); }
        MFMAQ(afB, bfB, 4, 2);
        BARRIER;
    }
    asm volatile("s_waitcnt vmcnt(0)" ::: "memory");

    // epilogue: C/D layout col=lane&15, row=(lane>>4)*4+reg  [verified m89/m91]
#pragma unroll
    for (int mi = 0; mi < 8; ++mi) {
#pragma unroll
        for (int i = 0; i < 4; ++i) {
            const int row = m0 + wr * 128 + mi * 16 + fq * 4 + i;
            const size_t base = (size_t)row * N + n0 + wc * 64 + fr;
#pragma unroll
            for (int ni = 0; ni < 4; ++ni) {
                if (BF16OUT)
                    ((unsigned short*)Cout)[base + ni * 16] = f2bf(acc[mi][ni][i]);
                else
                    ((float*)Cout)[base + ni * 16] = acc[mi][ni][i];
            }
        }
    }
#undef LDA
#undef LDB
#undef MFMAQ
}

// ---------------- GEMM: C[M,N] = A[M,K] * W[N,K]^T (m97 structure) ----------
template <bool BF16OUT>
__global__ __launch_bounds__(256) void gemm_bt(const unsigned short* __restrict__ A,
                                               const unsigned short* __restrict__ W,
                                               void* __restrict__ Cout,
                                               int M, int N, int K) {
    __shared__ unsigned short As[128 * 32];
    __shared__ unsigned short Bs[128 * 32];
    const int tid = threadIdx.x;
    const int w = tid >> 6, lane = tid & 63;
    const int fr = lane & 15, fq = lane >> 4;
    const int m0 = blockIdx.y * 128, n0 = blockIdx.x * 128;
    const int wr = w >> 1, wc = w & 1;

    f32x4 acc[4][4];
#pragma unroll
    for (int a = 0; a < 4; a++)
#pragma unroll
        for (int b = 0; b < 4; b++) acc[a][b] = f32x4{0.f, 0.f, 0.f, 0.f};

    const int srow = w * 16 + (lane >> 2);
    const int scol = (lane & 3) * 8;

    for (int kt = 0; kt < K; kt += 32) {
        __syncthreads();
#pragma unroll
        for (int it = 0; it < 2; ++it) {
            const unsigned short* ga = A + (size_t)(m0 + it * 64 + srow) * K + kt + scol;
            unsigned short* la = As + (it * 64 + w * 16) * 32;
            GLDS16(ga, la);
            const unsigned short* gb = W + (size_t)(n0 + it * 64 + srow) * K + kt + scol;
            unsigned short* lb = Bs + (it * 64 + w * 16) * 32;
            GLDS16(gb, lb);
        }
        asm volatile("s_waitcnt vmcnt(0)" ::: "memory");
        __syncthreads();

        bf16x8 af[4], bfr[4];
#pragma unroll
        for (int mi = 0; mi < 4; mi++)
            af[mi] = *reinterpret_cast<const bf16x8*>(As + (wr * 64 + mi * 16 + fr) * 32 + fq * 8);
#pragma unroll
        for (int ni = 0; ni < 4; ni++)
            bfr[ni] = *reinterpret_cast<const bf16x8*>(Bs + (wc * 64 + ni * 16 + fr) * 32 + fq * 8);
#pragma unroll
        for (int mi = 0; mi < 4; mi++)
#pragma unroll
            for (int ni = 0; ni < 4; ni++)
                acc[mi][ni] = MFMA(af[mi], bfr[ni], acc[mi][ni]);
    }

#pragma unroll
    for (int mi = 0; mi < 4; mi++) {
#pragma unroll
        for (int i = 0; i < 4; i++) {
            const int row = m0 + wr * 64 + mi * 16 + fq * 4 + i;
            const size_t base = (size_t)row * N + n0 + wc * 64 + fr;
#pragma unroll
            for (int ni = 0; ni < 4; ni++) {
                if (BF16OUT)
                    ((unsigned short*)Cout)[base + ni * 16] = f2bf(acc[mi][ni][i]);
                else
                    ((float*)Cout)[base + ni * 16] = acc[mi][ni][i];
            }
        }
    }
}

// ---------------- V transpose: qkv V-part [4096][2048] -> vT[2][2048][2048] --
__global__ __launch_bounds__(256) void transpose_v(const unsigned short* __restrict__ qkv,
                                                   unsigned short* __restrict__ vT) {
    __shared__ unsigned short t[32][33];
    const int b = blockIdx.z, ts = blockIdx.x, tu = blockIdx.y;
    const int i = threadIdx.x >> 5, j = threadIdx.x & 31;
#pragma unroll
    for (int ii = 0; ii < 4; ++ii) {
        const int row = i + ii * 8;
        t[row][j] = qkv[(size_t)(b * 2048 + ts * 32 + row) * 6144 + 4096 + tu * 32 + j];
    }
    __syncthreads();
#pragma unroll
    for (int ii = 0; ii < 4; ++ii) {
        const int row = i + ii * 8;
        vT[(size_t)(b * 2048 + tu * 32 + row) * 2048 + ts * 32 + j] = t[j][row];
    }
}

// ---------------- Flash attention, causal, block-cooperative ----------------
#define SM_SCALE 0.08838834764831845f

__global__ __launch_bounds__(256, 2) void attn_fwd(const unsigned short* __restrict__ qkv,
                                                   const unsigned short* __restrict__ vT,
                                                   unsigned short* __restrict__ ao) {
    __shared__ __align__(16) char Kt[2][8192];
    __shared__ __align__(16) char Vt[2][8192];
    __shared__ __align__(16) unsigned short Ps[4][16 * 40];
    const int tid = threadIdx.x;
    const int w = tid >> 6, lane = tid & 63;
    const int fr = lane & 15, fq = lane >> 4;
    const int t = blockIdx.x;
    const int bh = t & 31;
    const int g = 31 - (t >> 5);
    const int b = bh >> 4, h = bh & 15;
    const int q0 = g * 64 + w * 16;
    const int nb = 2 * g + 2;

    const unsigned short* Qb = qkv + (size_t)b * 2048 * 6144 + h * 128;
    const unsigned short* Kb = qkv + (size_t)b * 2048 * 6144 + (16 + h) * 128;
    const unsigned short* Vb = vT + (size_t)bh * 128 * 2048;

    bf16x8 qf[4];
    {
        const unsigned short* qr = Qb + (size_t)(q0 + fr) * 6144 + fq * 8;
#pragma unroll
        for (int c = 0; c < 4; c++) qf[c] = *reinterpret_cast<const bf16x8*>(qr + c * 32);
    }

    f32x4 acc[8];
#pragma unroll
    for (int f = 0; f < 8; f++) acc[f] = f32x4{0.f, 0.f, 0.f, 0.f};
    float m_r[4], l_r[4];
#pragma unroll
    for (int i = 0; i < 4; i++) { m_r[i] = -__builtin_inff(); l_r[i] = 0.f; }

    unsigned short* Pw = &Ps[w][0];

    auto stage = [&](int kbs, int bufi) {
        const int k0s = kbs * 32;
        if (w < 2) {
#pragma unroll
            for (int q = 0; q < 4; ++q) {
                const int i = w * 4 + q;
                const int r = 4 * i + (lane >> 4);
                const int ce = ((((lane & 15) * 16) ^ ((r & 7) << 4))) >> 1;
                const unsigned short* gp = Kb + (size_t)(k0s + r) * 6144 + ce;
                GLDS16(gp, &Kt[bufi][i * 1024]);
            }
        } else {
#pragma unroll
            for (int q = 0; q < 4; ++q) {
                const int i = (w - 2) * 4 + q;
                const int r = 16 * i + (lane >> 2);
                const int ce = ((lane & 3) ^ ((lane >> 3) & 3)) * 8;
                const unsigned short* gp = Vb + (size_t)r * 2048 + k0s + ce;
                GLDS16(gp, &Vt[bufi][i * 1024]);
            }
        }
    };

    int cur = 0;
    stage(0, 0);
    __syncthreads();

    for (int kb = 0; kb < nb; ++kb) {
        if (kb + 1 < nb) stage(kb + 1, cur ^ 1);
        const int k0 = kb * 32;
        if (k0 <= q0 + 15) {
            const char* Kl = &Kt[cur][0];
            const char* Vl = &Vt[cur][0];
            bf16x8 kf[2][4];
#pragma unroll
            for (int t2 = 0; t2 < 2; t2++)
#pragma unroll
                for (int c = 0; c < 4; c++)
                    kf[t2][c] = *reinterpret_cast<const bf16x8*>(
                        Kl + (t2 * 16 + fr) * 256 + ((c * 64 + fq * 16) ^ ((fr & 7) << 4)));
            f32x4 s0 = f32x4{0.f, 0.f, 0.f, 0.f}, s1 = f32x4{0.f, 0.f, 0.f, 0.f};
            __builtin_amdgcn_s_setprio(1);
#pragma unroll
            for (int c = 0; c < 4; c++) {
                s0 = MFMA(qf[c], kf[0][c], s0);
                s1 = MFMA(qf[c], kf[1][c], s1);
            }
            __builtin_amdgcn_s_setprio(0);
            bf16x8 vf[8];
#pragma unroll
            for (int f = 0; f < 8; f++)
                vf[f] = *reinterpret_cast<const bf16x8*>(
                    Vl + (f * 16 + fr) * 64 + ((fq * 16) ^ (((fr >> 1) & 3) << 4)));

            const bool msk = (k0 + 31 > q0);
            float a0_[4], a1_[4], mx_[4];
#pragma unroll
            for (int i = 0; i < 4; i++) {
                const int qrow = q0 + fq * 4 + i;
                a0_[i] = s0[i] * SM_SCALE; a1_[i] = s1[i] * SM_SCALE;
                if (msk) {
                    if (k0 + fr > qrow) a0_[i] = -__builtin_inff();
                    if (k0 + 16 + fr > qrow) a1_[i] = -__builtin_inff();
                }
                mx_[i] = fmaxf(a0_[i], a1_[i]);
            }
#pragma unroll
            for (int st = 1; st <= 8; st <<= 1) {
#pragma unroll
                for (int i = 0; i < 4; i++) mx_[i] = fmaxf(mx_[i], __shfl_xor(mx_[i], st, 64));
            }
            float p0_[4], p1_[4], su_[4];
#pragma unroll
            for (int i = 0; i < 4; i++) {
                const float mn = fmaxf(m_r[i], mx_[i]);
                const float corr = __expf(m_r[i] - mn);
                p0_[i] = __expf(a0_[i] - mn);
                p1_[i] = __expf(a1_[i] - mn);
                su_[i] = p0_[i] + p1_[i];
                m_r[i] = mn; l_r[i] *= corr;
#pragma unroll
                for (int f = 0; f < 8; f++) acc[f][i] *= corr;
            }
#pragma unroll
            for (int st = 1; st <= 8; st <<= 1) {
#pragma unroll
                for (int i = 0; i < 4; i++) su_[i] += __shfl_xor(su_[i], st, 64);
            }
#pragma unroll
            for (int i = 0; i < 4; i++) {
                l_r[i] += su_[i];
                Pw[(fq * 4 + i) * 40 + fr] = f2bf(p0_[i]);
                Pw[(fq * 4 + i) * 40 + 16 + fr] = f2bf(p1_[i]);
            }
            bf16x8 pa = *reinterpret_cast<const bf16x8*>(Pw + fr * 40 + fq * 8);
            __builtin_amdgcn_s_setprio(1);
#pragma unroll
            for (int f = 0; f < 8; f++) acc[f] = MFMA(pa, vf[f], acc[f]);
            __builtin_amdgcn_s_setprio(0);
        }
        __syncthreads();
        cur ^= 1;
    }

#pragma unroll
    for (int f = 0; f < 8; f++) {
#pragma unroll
        for (int i = 0; i < 4; i++) {
            const int qrow = q0 + fq * 4 + i;
            const float o = acc[f][i] / l_r[i];
            ao[(size_t)(b * 2048 + qrow) * 2048 + h * 128 + f * 16 + fr] = f2bf(o);
        }
    }
}

// ---------------------------------------------------------------------------
extern "C" void kernel_launch(void* const* d_in, const int* in_sizes, int n_in,
                              void* d_out, int out_size, void* d_ws, size_t ws_size,
                              hipStream_t stream) {
    const float* x    = (const float*)d_in[0];
    const float* Wqkv = (const float*)d_in[1];
    const float* Wout = (const float*)d_in[2];
    float* out = (float*)d_out;

    char* ws = (char*)d_ws;
    unsigned short* xb    = (unsigned short*)(ws);
    unsigned short* wqkvb = (unsigned short*)(ws + (size_t)(16 << 20));
    unsigned short* woutb = (unsigned short*)(ws + (size_t)(40 << 20));
    unsigned short* qkvb  = (unsigned short*)(ws + (size_t)(48 << 20));
    unsigned short* vTb   = (unsigned short*)(ws + (size_t)(16 << 20)); // over wqkvb
    unsigned short* attnb = (unsigned short*)(ws);                      // over xb

    cvt_f32_bf16<<<8192, 256, 0, stream>>>(x, xb, 2097152);
    cvt_f32_bf16<<<12288, 256, 0, stream>>>(Wqkv, wqkvb, 3145728);
    cvt_f32_bf16<<<4096, 256, 0, stream>>>(Wout, woutb, 1048576);

    // qkv = x @ W_qkv^T : M=4096, N=6144, K=2048 -> 16x24=384 blocks (384%8==0)
    gemm256<true><<<384, 512, 0, stream>>>(xb, wqkvb, qkvb, 4096, 6144, 2048);

    // vT[b][h*128+dk][s] = V[b][s][h*128+dk]
    transpose_v<<<dim3(64, 64, 2), 256, 0, stream>>>(qkvb, vTb);

    // causal flash attention -> attnb (bf16 [4096][2048])
    attn_fwd<<<1024, 256, 0, stream>>>(qkvb, vTb, attnb);

    // out = attnb @ W_out^T : M=4096, N=2048, K=2048, fp32 out
    gemm_bt<false><<<dim3(16, 32), 256, 0, stream>>>(attnb, woutb, out, 4096, 2048, 2048);
}

// Round 6
// 316.438 us; speedup vs baseline: 1.1175x; 1.1175x over previous
//
#include <hip/hip_runtime.h>
#include <hip/hip_bf16.h>

// ---------------------------------------------------------------------------
// MultiHeadAttention: x[2,2048,2048] f32, W_qkv[6144,2048], W_out[2048,2048]
// out = MHA(x) in fp32. Internally bf16 MFMA with fp32 accumulation.
// ---------------------------------------------------------------------------

typedef short bf16x8 __attribute__((ext_vector_type(8)));
typedef float f32x4  __attribute__((ext_vector_type(4)));

#define MFMA(a, b, c) __builtin_amdgcn_mfma_f32_16x16x32_bf16((a), (b), (c), 0, 0, 0)

#define GLDS16(gp, lp) __builtin_amdgcn_global_load_lds(                        \
    (const __attribute__((address_space(1))) void*)(gp),                        \
    (__attribute__((address_space(3))) void*)(lp), 16, 0, 0)

static __device__ __forceinline__ unsigned short f2bf(float f) {
    __hip_bfloat16 h = __float2bfloat16(f);
    return *reinterpret_cast<unsigned short*>(&h);
}

// ---------------- fp32 -> bf16 convert (vectorized) ------------------------
__global__ __launch_bounds__(256) void cvt_f32_bf16(const float* __restrict__ in,
                                                    unsigned short* __restrict__ out,
                                                    int n4) {
    int i = blockIdx.x * 256 + threadIdx.x;
    if (i < n4) {
        float4 v = reinterpret_cast<const float4*>(in)[i];
        ushort4 o;
        o.x = f2bf(v.x); o.y = f2bf(v.y); o.z = f2bf(v.z); o.w = f2bf(v.w);
        reinterpret_cast<ushort4*>(out)[i] = o;
    }
}

// ---------------- GEMM: C[M,N] = A[M,K] * W[N,K]^T (m97 structure) ----------
// 128x128 tile, BK=32, 4 waves (2x2 of 64x64), global_load_lds width 16.
template <bool BF16OUT>
__global__ __launch_bounds__(256) void gemm_bt(const unsigned short* __restrict__ A,
                                               const unsigned short* __restrict__ W,
                                               void* __restrict__ Cout,
                                               int M, int N, int K) {
    __shared__ unsigned short As[128 * 32];
    __shared__ unsigned short Bs[128 * 32];
    const int tid = threadIdx.x;
    const int w = tid >> 6, lane = tid & 63;
    const int fr = lane & 15, fq = lane >> 4;
    const int m0 = blockIdx.y * 128, n0 = blockIdx.x * 128;
    const int wr = w >> 1, wc = w & 1;

    f32x4 acc[4][4];
#pragma unroll
    for (int a = 0; a < 4; a++)
#pragma unroll
        for (int b = 0; b < 4; b++) acc[a][b] = f32x4{0.f, 0.f, 0.f, 0.f};

    const int srow = w * 16 + (lane >> 2);
    const int scol = (lane & 3) * 8;

    for (int kt = 0; kt < K; kt += 32) {
        __syncthreads();
#pragma unroll
        for (int it = 0; it < 2; ++it) {
            const unsigned short* ga = A + (size_t)(m0 + it * 64 + srow) * K + kt + scol;
            unsigned short* la = As + (it * 64 + w * 16) * 32;
            GLDS16(ga, la);
            const unsigned short* gb = W + (size_t)(n0 + it * 64 + srow) * K + kt + scol;
            unsigned short* lb = Bs + (it * 64 + w * 16) * 32;
            GLDS16(gb, lb);
        }
        asm volatile("s_waitcnt vmcnt(0)" ::: "memory");
        __syncthreads();

        bf16x8 af[4], bfr[4];
#pragma unroll
        for (int mi = 0; mi < 4; mi++)
            af[mi] = *reinterpret_cast<const bf16x8*>(As + (wr * 64 + mi * 16 + fr) * 32 + fq * 8);
#pragma unroll
        for (int ni = 0; ni < 4; ni++)
            bfr[ni] = *reinterpret_cast<const bf16x8*>(Bs + (wc * 64 + ni * 16 + fr) * 32 + fq * 8);
#pragma unroll
        for (int mi = 0; mi < 4; mi++)
#pragma unroll
            for (int ni = 0; ni < 4; ni++)
                acc[mi][ni] = MFMA(af[mi], bfr[ni], acc[mi][ni]);
    }

    // epilogue: C/D layout col=lane&15, row=(lane>>4)*4+reg  [verified m89/m91]
#pragma unroll
    for (int mi = 0; mi < 4; mi++) {
#pragma unroll
        for (int i = 0; i < 4; i++) {
            const int row = m0 + wr * 64 + mi * 16 + fq * 4 + i;
            const size_t base = (size_t)row * N + n0 + wc * 64 + fr;
#pragma unroll
            for (int ni = 0; ni < 4; ni++) {
                if (BF16OUT)
                    ((unsigned short*)Cout)[base + ni * 16] = f2bf(acc[mi][ni][i]);
                else
                    ((float*)Cout)[base + ni * 16] = acc[mi][ni][i];
            }
        }
    }
}

// ---------------- V transpose: qkv V-part [4096][2048] -> vT[2][2048][2048] --
__global__ __launch_bounds__(256) void transpose_v(const unsigned short* __restrict__ qkv,
                                                   unsigned short* __restrict__ vT) {
    __shared__ unsigned short t[32][33];
    const int b = blockIdx.z, ts = blockIdx.x, tu = blockIdx.y;
    const int i = threadIdx.x >> 5, j = threadIdx.x & 31;
#pragma unroll
    for (int ii = 0; ii < 4; ++ii) {
        const int row = i + ii * 8;
        t[row][j] = qkv[(size_t)(b * 2048 + ts * 32 + row) * 6144 + 4096 + tu * 32 + j];
    }
    __syncthreads();
#pragma unroll
    for (int ii = 0; ii < 4; ++ii) {
        const int row = i + ii * 8;
        vT[(size_t)(b * 2048 + tu * 32 + row) * 2048 + ts * 32 + j] = t[j][row];
    }
}

// ---------------- Flash attention, causal, block-cooperative, KVBLK=64 ------
// Block = one (b,h), 64-row q-supertile, 4 waves x 16 q-rows. Per kv-iter the
// block stages K[64][128] (16KB) and Vt[128][64] (16KB) into double-buffered
// LDS via global_load_lds (coalesced, pre-swizzled source, swizzled reads).
// Both use byte ^= ((row&7)<<4) within the row (K row=256B, Vt row=128B).
// Halved per-kv sync/softmax cost vs KVBLK=32: 1 barrier + 8 shfl-stages +
// 1 P-roundtrip + 1 rescale per 64 kv. QK and PV each processed in two
// register-reusing halves to cap VGPR.
#define SM_SCALE 0.08838834764831845f

__global__ __launch_bounds__(256, 2) void attn_fwd(const unsigned short* __restrict__ qkv,
                                                   const unsigned short* __restrict__ vT,
                                                   unsigned short* __restrict__ ao) {
    __shared__ __align__(16) char Kt[2][16384];   // 64 rows x 256B
    __shared__ __align__(16) char Vt[2][16384];   // 128 rows x 128B
    __shared__ __align__(16) unsigned short Ps[4][16 * 72];  // 16 x 64, stride 72
    const int tid = threadIdx.x;
    const int w = tid >> 6, lane = tid & 63;
    const int fr = lane & 15, fq = lane >> 4;
    const int t = blockIdx.x;           // 1024 blocks
    const int bh = t & 31;              // bh%8 ~ XCD id: 4 heads per XCD L2
    const int g = 31 - (t >> 5);        // heavy (large q0) supertiles first
    const int b = bh >> 4, h = bh & 15;
    const int q0 = g * 64 + w * 16;     // this wave's 16 q-rows
    const int nb = g + 1;               // 64-wide kv blocks

    const unsigned short* Qb = qkv + (size_t)b * 2048 * 6144 + h * 128;
    const unsigned short* Kb = qkv + (size_t)b * 2048 * 6144 + (16 + h) * 128;
    const unsigned short* Vb = vT + (size_t)bh * 128 * 2048;

    bf16x8 qf[4];
    {
        const unsigned short* qr = Qb + (size_t)(q0 + fr) * 6144 + fq * 8;
#pragma unroll
        for (int c = 0; c < 4; c++) qf[c] = *reinterpret_cast<const bf16x8*>(qr + c * 32);
    }

    f32x4 acc[8];
#pragma unroll
    for (int f = 0; f < 8; f++) acc[f] = f32x4{0.f, 0.f, 0.f, 0.f};
    float m_r[4], l_r[4];
#pragma unroll
    for (int i = 0; i < 4; i++) { m_r[i] = -__builtin_inff(); l_r[i] = 0.f; }

    unsigned short* Pw = &Ps[w][0];

    // staging: waves 0,1 -> K (16 x 1KB instr), waves 2,3 -> Vt (16 x 1KB).
    // K instr i: rows 4i..4i+3 (256B); lane l -> row 4i+(l>>4),
    //   src col elem = (((l&15)*16) ^ ((r&7)<<4)) >> 1.
    // V instr i: rows 8i..8i+7 (128B); lane l -> row 8i+(l>>3),
    //   src col elem = ((l&7) ^ ((l>>3)&7)) * 8.
    auto stage = [&](int kbs, int bufi) {
        const int k0s = kbs * 64;
        if (w < 2) {
#pragma unroll
            for (int q = 0; q < 8; ++q) {
                const int i = w * 8 + q;
                const int r = 4 * i + (lane >> 4);
                const int ce = ((((lane & 15) * 16) ^ ((r & 7) << 4))) >> 1;
                GLDS16(Kb + (size_t)(k0s + r) * 6144 + ce, &Kt[bufi][i * 1024]);
            }
        } else {
#pragma unroll
            for (int q = 0; q < 8; ++q) {
                const int i = (w - 2) * 8 + q;
                const int r = 8 * i + (lane >> 3);
                const int ce = ((lane & 7) ^ ((lane >> 3) & 7)) * 8;
                GLDS16(Vb + (size_t)r * 2048 + k0s + ce, &Vt[bufi][i * 1024]);
            }
        }
    };

    int cur = 0;
    stage(0, 0);
    __syncthreads();

    for (int kb = 0; kb < nb; ++kb) {
        if (kb + 1 < nb) stage(kb + 1, cur ^ 1);
        const int k0 = kb * 64;
        const char* Kl = &Kt[cur][0];
        const char* Vl = &Vt[cur][0];

        // ---- QK^T: 4 16-col score tiles, two register-reusing halves ----
        f32x4 s[4];
#pragma unroll
        for (int th = 0; th < 2; ++th) {
            bf16x8 kf[2][4];
#pragma unroll
            for (int t2 = 0; t2 < 2; ++t2) {
                const int tt = th * 2 + t2;
#pragma unroll
                for (int c = 0; c < 4; ++c)
                    kf[t2][c] = *reinterpret_cast<const bf16x8*>(
                        Kl + (tt * 16 + fr) * 256 + ((c * 64 + fq * 16) ^ ((fr & 7) << 4)));
            }
            f32x4 a0 = f32x4{0.f, 0.f, 0.f, 0.f}, a1 = f32x4{0.f, 0.f, 0.f, 0.f};
            __builtin_amdgcn_s_setprio(1);
#pragma unroll
            for (int c = 0; c < 4; ++c) {
                a0 = MFMA(qf[c], kf[0][c], a0);
                a1 = MFMA(qf[c], kf[1][c], a1);
            }
            __builtin_amdgcn_s_setprio(0);
            s[th * 2] = a0; s[th * 2 + 1] = a1;
        }

        // ---- softmax (online, per q-row; rows split i=0..3 over fq groups) --
        const bool diag = (kb == nb - 1);   // wave-uniform
        float p[4][4], mx[4];
#pragma unroll
        for (int i = 0; i < 4; ++i) {
            const int qrow = q0 + fq * 4 + i;
#pragma unroll
            for (int tt = 0; tt < 4; ++tt) {
                float a = s[tt][i] * SM_SCALE;
                if (diag && (k0 + tt * 16 + fr > qrow)) a = -__builtin_inff();
                p[tt][i] = a;
            }
            mx[i] = fmaxf(fmaxf(p[0][i], p[1][i]), fmaxf(p[2][i], p[3][i]));
        }
#pragma unroll
        for (int st = 1; st <= 8; st <<= 1) {
#pragma unroll
            for (int i = 0; i < 4; i++) mx[i] = fmaxf(mx[i], __shfl_xor(mx[i], st, 64));
        }
        float su[4];
#pragma unroll
        for (int i = 0; i < 4; ++i) {
            const float mn = fmaxf(m_r[i], mx[i]);
            const float corr = __expf(m_r[i] - mn);
#pragma unroll
            for (int tt = 0; tt < 4; ++tt) p[tt][i] = __expf(p[tt][i] - mn);
            su[i] = (p[0][i] + p[1][i]) + (p[2][i] + p[3][i]);
            m_r[i] = mn; l_r[i] *= corr;
#pragma unroll
            for (int f = 0; f < 8; f++) acc[f][i] *= corr;
        }
#pragma unroll
        for (int st = 1; st <= 8; st <<= 1) {
#pragma unroll
            for (int i = 0; i < 4; i++) su[i] += __shfl_xor(su[i], st, 64);
        }
#pragma unroll
        for (int i = 0; i < 4; ++i) {
            l_r[i] += su[i];
#pragma unroll
            for (int tt = 0; tt < 4; ++tt)
                Pw[(fq * 4 + i) * 72 + tt * 16 + fr] = f2bf(p[tt][i]);
        }

        // ---- PV: two kv-halves of 32, register-reusing vf ----
#pragma unroll
        for (int h2 = 0; h2 < 2; ++h2) {
            bf16x8 pa = *reinterpret_cast<const bf16x8*>(Pw + fr * 72 + h2 * 32 + fq * 8);
            bf16x8 vf[8];
#pragma unroll
            for (int f = 0; f < 8; ++f)
                vf[f] = *reinterpret_cast<const bf16x8*>(
                    Vl + (f * 16 + fr) * 128 + ((h2 * 64 + fq * 16) ^ ((fr & 7) << 4)));
            __builtin_amdgcn_s_setprio(1);
#pragma unroll
            for (int f = 0; f < 8; ++f) acc[f] = MFMA(pa, vf[f], acc[f]);
            __builtin_amdgcn_s_setprio(0);
        }

        __syncthreads();
        cur ^= 1;
    }

    // epilogue: normalize and store bf16 [4096][2048]
#pragma unroll
    for (int f = 0; f < 8; f++) {
#pragma unroll
        for (int i = 0; i < 4; i++) {
            const int qrow = q0 + fq * 4 + i;
            const float o = acc[f][i] / l_r[i];
            ao[(size_t)(b * 2048 + qrow) * 2048 + h * 128 + f * 16 + fr] = f2bf(o);
        }
    }
}

// ---------------------------------------------------------------------------
extern "C" void kernel_launch(void* const* d_in, const int* in_sizes, int n_in,
                              void* d_out, int out_size, void* d_ws, size_t ws_size,
                              hipStream_t stream) {
    const float* x    = (const float*)d_in[0];
    const float* Wqkv = (const float*)d_in[1];
    const float* Wout = (const float*)d_in[2];
    float* out = (float*)d_out;

    // Workspace layout (96 MB), regions reused across phases:
    //   [0,16M):   xb (bf16 x), later reused as attnb
    //   [16M,40M): wqkvb (24M), later reused as vT (16M)
    //   [40M,48M): woutb
    //   [48M,96M): qkvb (bf16 [4096][6144])
    char* ws = (char*)d_ws;
    unsigned short* xb    = (unsigned short*)(ws);
    unsigned short* wqkvb = (unsigned short*)(ws + (size_t)(16 << 20));
    unsigned short* woutb = (unsigned short*)(ws + (size_t)(40 << 20));
    unsigned short* qkvb  = (unsigned short*)(ws + (size_t)(48 << 20));
    unsigned short* vTb   = (unsigned short*)(ws + (size_t)(16 << 20)); // over wqkvb
    unsigned short* attnb = (unsigned short*)(ws);                      // over xb

    cvt_f32_bf16<<<8192, 256, 0, stream>>>(x, xb, 2097152);
    cvt_f32_bf16<<<12288, 256, 0, stream>>>(Wqkv, wqkvb, 3145728);
    cvt_f32_bf16<<<4096, 256, 0, stream>>>(Wout, woutb, 1048576);

    // qkv = x @ W_qkv^T : M=4096, N=6144, K=2048, bf16 out
    gemm_bt<true><<<dim3(48, 32), 256, 0, stream>>>(xb, wqkvb, qkvb, 4096, 6144, 2048);

    // vT[b][h*128+dk][s] = V[b][s][h*128+dk]  (wqkvb dead after the GEMM)
    transpose_v<<<dim3(64, 64, 2), 256, 0, stream>>>(qkvb, vTb);

    // causal flash attention -> attnb (bf16 [4096][2048])  (xb dead now)
    attn_fwd<<<1024, 256, 0, stream>>>(qkvb, vTb, attnb);

    // out = attnb @ W_out^T : M=4096, N=2048, K=2048, fp32 out
    gemm_bt<false><<<dim3(16, 32), 256, 0, stream>>>(attnb, woutb, out, 4096, 2048, 2048);
}

// Round 7
// 314.460 us; speedup vs baseline: 1.1246x; 1.0063x over previous
//
#include <hip/hip_runtime.h>
#include <hip/hip_bf16.h>

// ---------------------------------------------------------------------------
// MultiHeadAttention: x[2,2048,2048] f32, W_qkv[6144,2048], W_out[2048,2048]
// out = MHA(x) in fp32. Internally bf16 MFMA with fp32 accumulation.
// ---------------------------------------------------------------------------

typedef short bf16x8 __attribute__((ext_vector_type(8)));
typedef float f32x4  __attribute__((ext_vector_type(4)));

#define MFMA(a, b, c) __builtin_amdgcn_mfma_f32_16x16x32_bf16((a), (b), (c), 0, 0, 0)

#define GLDS16(gp, lp) __builtin_amdgcn_global_load_lds(                        \
    (const __attribute__((address_space(1))) void*)(gp),                        \
    (__attribute__((address_space(3))) void*)(lp), 16, 0, 0)

static __device__ __forceinline__ unsigned short f2bf(float f) {
    __hip_bfloat16 h = __float2bfloat16(f);
    return *reinterpret_cast<unsigned short*>(&h);
}

// ---------------- fp32 -> bf16 convert (vectorized) ------------------------
__global__ __launch_bounds__(256) void cvt_f32_bf16(const float* __restrict__ in,
                                                    unsigned short* __restrict__ out,
                                                    int n4) {
    int i = blockIdx.x * 256 + threadIdx.x;
    if (i < n4) {
        float4 v = reinterpret_cast<const float4*>(in)[i];
        ushort4 o;
        o.x = f2bf(v.x); o.y = f2bf(v.y); o.z = f2bf(v.z); o.w = f2bf(v.w);
        reinterpret_cast<ushort4*>(out)[i] = o;
    }
}

// ---------------- GEMM: C[M,N] = A[M,K] * W[N,K]^T (m97 structure) ----------
// 128x128 tile, BK=32, 4 waves (2x2 of 64x64), global_load_lds width 16.
template <bool BF16OUT>
__global__ __launch_bounds__(256) void gemm_bt(const unsigned short* __restrict__ A,
                                               const unsigned short* __restrict__ W,
                                               void* __restrict__ Cout,
                                               int M, int N, int K) {
    __shared__ unsigned short As[128 * 32];
    __shared__ unsigned short Bs[128 * 32];
    const int tid = threadIdx.x;
    const int w = tid >> 6, lane = tid & 63;
    const int fr = lane & 15, fq = lane >> 4;
    const int m0 = blockIdx.y * 128, n0 = blockIdx.x * 128;
    const int wr = w >> 1, wc = w & 1;

    f32x4 acc[4][4];
#pragma unroll
    for (int a = 0; a < 4; a++)
#pragma unroll
        for (int b = 0; b < 4; b++) acc[a][b] = f32x4{0.f, 0.f, 0.f, 0.f};

    const int srow = w * 16 + (lane >> 2);
    const int scol = (lane & 3) * 8;

    for (int kt = 0; kt < K; kt += 32) {
        __syncthreads();
#pragma unroll
        for (int it = 0; it < 2; ++it) {
            const unsigned short* ga = A + (size_t)(m0 + it * 64 + srow) * K + kt + scol;
            unsigned short* la = As + (it * 64 + w * 16) * 32;
            GLDS16(ga, la);
            const unsigned short* gb = W + (size_t)(n0 + it * 64 + srow) * K + kt + scol;
            unsigned short* lb = Bs + (it * 64 + w * 16) * 32;
            GLDS16(gb, lb);
        }
        asm volatile("s_waitcnt vmcnt(0)" ::: "memory");
        __syncthreads();

        bf16x8 af[4], bfr[4];
#pragma unroll
        for (int mi = 0; mi < 4; mi++)
            af[mi] = *reinterpret_cast<const bf16x8*>(As + (wr * 64 + mi * 16 + fr) * 32 + fq * 8);
#pragma unroll
        for (int ni = 0; ni < 4; ni++)
            bfr[ni] = *reinterpret_cast<const bf16x8*>(Bs + (wc * 64 + ni * 16 + fr) * 32 + fq * 8);
#pragma unroll
        for (int mi = 0; mi < 4; mi++)
#pragma unroll
            for (int ni = 0; ni < 4; ni++)
                acc[mi][ni] = MFMA(af[mi], bfr[ni], acc[mi][ni]);
    }

    // epilogue: C/D layout col=lane&15, row=(lane>>4)*4+reg  [verified m89/m91]
#pragma unroll
    for (int mi = 0; mi < 4; mi++) {
#pragma unroll
        for (int i = 0; i < 4; i++) {
            const int row = m0 + wr * 64 + mi * 16 + fq * 4 + i;
            const size_t base = (size_t)row * N + n0 + wc * 64 + fr;
#pragma unroll
            for (int ni = 0; ni < 4; ni++) {
                if (BF16OUT)
                    ((unsigned short*)Cout)[base + ni * 16] = f2bf(acc[mi][ni][i]);
                else
                    ((float*)Cout)[base + ni * 16] = acc[mi][ni][i];
            }
        }
    }
}

// ---------------- V transpose: qkv V-part [4096][2048] -> vT[2][2048][2048] --
__global__ __launch_bounds__(256) void transpose_v(const unsigned short* __restrict__ qkv,
                                                   unsigned short* __restrict__ vT) {
    __shared__ unsigned short t[32][33];
    const int b = blockIdx.z, ts = blockIdx.x, tu = blockIdx.y;
    const int i = threadIdx.x >> 5, j = threadIdx.x & 31;
#pragma unroll
    for (int ii = 0; ii < 4; ++ii) {
        const int row = i + ii * 8;
        t[row][j] = qkv[(size_t)(b * 2048 + ts * 32 + row) * 6144 + 4096 + tu * 32 + j];
    }
    __syncthreads();
#pragma unroll
    for (int ii = 0; ii < 4; ++ii) {
        const int row = i + ii * 8;
        vT[(size_t)(b * 2048 + tu * 32 + row) * 2048 + ts * 32 + j] = t[j][row];
    }
}

// ---------------- Flash attention, causal, block-cooperative, KVBLK=64 ------
// 512 blocks, each = one (b,h) x TWO 64-row q-supertiles {g=31-j, g=j} run
// sequentially -> exactly 33 kv-iterations per block (perfect static balance;
// 512 blocks = 2/CU all-resident, zero tail). Per kv-iter the block stages
// K[64][128] (16KB) and Vt[128][64] (16KB) into double-buffered LDS via
// global_load_lds (coalesced, pre-swizzled source, XOR-swizzled reads,
// byte ^= ((row&7)<<4)). Softmax in exp2 domain (scale folded); T13
// defer-rescale (THR=8) skips the acc-rescale pass when max is stable.
#define SC2 (0.08838834764831845f * 1.4426950408889634f)  // SM_SCALE*log2(e)

__global__ __launch_bounds__(256, 2) void attn_fwd(const unsigned short* __restrict__ qkv,
                                                   const unsigned short* __restrict__ vT,
                                                   unsigned short* __restrict__ ao) {
    __shared__ __align__(16) char Kt[2][16384];   // 64 rows x 256B
    __shared__ __align__(16) char Vt[2][16384];   // 128 rows x 128B
    __shared__ __align__(16) unsigned short Ps[4][16 * 72];  // 16 x 64, stride 72
    const int tid = threadIdx.x;
    const int w = tid >> 6, lane = tid & 63;
    const int fr = lane & 15, fq = lane >> 4;
    const int t = blockIdx.x;           // 512 blocks
    const int bh = t & 31;              // bh%8 ~ XCD id: 4 heads per XCD L2
    const int j = t >> 5;               // 0..15 -> pair {31-j, j}
    const int b = bh >> 4, h = bh & 15;

    const unsigned short* Qb = qkv + (size_t)b * 2048 * 6144 + h * 128;
    const unsigned short* Kb = qkv + (size_t)b * 2048 * 6144 + (16 + h) * 128;
    const unsigned short* Vb = vT + (size_t)bh * 128 * 2048;

    unsigned short* Pw = &Ps[w][0];

    // staging: waves 0,1 -> K (16 x 1KB instr), waves 2,3 -> Vt (16 x 1KB).
    auto stage = [&](int kbs, int bufi) {
        const int k0s = kbs * 64;
        if (w < 2) {
#pragma unroll
            for (int q = 0; q < 8; ++q) {
                const int i = w * 8 + q;
                const int r = 4 * i + (lane >> 4);
                const int ce = ((((lane & 15) * 16) ^ ((r & 7) << 4))) >> 1;
                GLDS16(Kb + (size_t)(k0s + r) * 6144 + ce, &Kt[bufi][i * 1024]);
            }
        } else {
#pragma unroll
            for (int q = 0; q < 8; ++q) {
                const int i = (w - 2) * 8 + q;
                const int r = 8 * i + (lane >> 3);
                const int ce = ((lane & 7) ^ ((lane >> 3) & 7)) * 8;
                GLDS16(Vb + (size_t)r * 2048 + k0s + ce, &Vt[bufi][i * 1024]);
            }
        }
    };

#pragma unroll 1
    for (int seg = 0; seg < 2; ++seg) {
        const int g = seg ? j : 31 - j;   // heavy supertile first
        const int q0 = g * 64 + w * 16;
        const int nb = g + 1;

        bf16x8 qf[4];
        {
            const unsigned short* qr = Qb + (size_t)(q0 + fr) * 6144 + fq * 8;
#pragma unroll
            for (int c = 0; c < 4; c++) qf[c] = *reinterpret_cast<const bf16x8*>(qr + c * 32);
        }

        f32x4 acc[8];
#pragma unroll
        for (int f = 0; f < 8; f++) acc[f] = f32x4{0.f, 0.f, 0.f, 0.f};
        float m_r[4], l_r[4];
#pragma unroll
        for (int i = 0; i < 4; i++) { m_r[i] = -__builtin_inff(); l_r[i] = 0.f; }

        int cur = 0;
        stage(0, 0);
        __syncthreads();

        for (int kb = 0; kb < nb; ++kb) {
            if (kb + 1 < nb) stage(kb + 1, cur ^ 1);
            const int k0 = kb * 64;
            const char* Kl = &Kt[cur][0];
            const char* Vl = &Vt[cur][0];

            // ---- QK^T: 4 16-col score tiles, two register-reusing halves ----
            f32x4 s[4];
#pragma unroll
            for (int th = 0; th < 2; ++th) {
                bf16x8 kf[2][4];
#pragma unroll
                for (int t2 = 0; t2 < 2; ++t2) {
                    const int tt = th * 2 + t2;
#pragma unroll
                    for (int c = 0; c < 4; ++c)
                        kf[t2][c] = *reinterpret_cast<const bf16x8*>(
                            Kl + (tt * 16 + fr) * 256 + ((c * 64 + fq * 16) ^ ((fr & 7) << 4)));
                }
                f32x4 a0 = f32x4{0.f, 0.f, 0.f, 0.f}, a1 = f32x4{0.f, 0.f, 0.f, 0.f};
                __builtin_amdgcn_s_setprio(1);
#pragma unroll
                for (int c = 0; c < 4; ++c) {
                    a0 = MFMA(qf[c], kf[0][c], a0);
                    a1 = MFMA(qf[c], kf[1][c], a1);
                }
                __builtin_amdgcn_s_setprio(0);
                s[th * 2] = a0; s[th * 2 + 1] = a1;
            }

            // ---- online softmax, exp2 domain; p[tt][i] = 2^(a - m) ----
            const bool diag = (kb == nb - 1);   // wave-uniform
            float p[4][4], mx[4];
#pragma unroll
            for (int i = 0; i < 4; ++i) {
                const int qrow = q0 + fq * 4 + i;
#pragma unroll
                for (int tt = 0; tt < 4; ++tt) {
                    float a = s[tt][i] * SC2;
                    if (diag && (k0 + tt * 16 + fr > qrow)) a = -__builtin_inff();
                    p[tt][i] = a;
                }
                mx[i] = fmaxf(fmaxf(p[0][i], p[1][i]), fmaxf(p[2][i], p[3][i]));
            }
#pragma unroll
            for (int st = 1; st <= 8; st <<= 1) {
#pragma unroll
                for (int i = 0; i < 4; i++) mx[i] = fmaxf(mx[i], __shfl_xor(mx[i], st, 64));
            }
            // T13 defer-rescale: only rescale when some row grew past THR=8.
            bool grow = false;
#pragma unroll
            for (int i = 0; i < 4; ++i) grow = grow || (mx[i] > m_r[i] + 8.0f);
            if (__any((int)grow)) {
#pragma unroll
                for (int i = 0; i < 4; ++i) {
                    const float mn = fmaxf(m_r[i], mx[i]);
                    const float corr = exp2f(m_r[i] - mn);
                    m_r[i] = mn; l_r[i] *= corr;
#pragma unroll
                    for (int f = 0; f < 8; f++) acc[f][i] *= corr;
                }
            }
            float su[4];
#pragma unroll
            for (int i = 0; i < 4; ++i) {
#pragma unroll
                for (int tt = 0; tt < 4; ++tt) p[tt][i] = exp2f(p[tt][i] - m_r[i]);
                su[i] = (p[0][i] + p[1][i]) + (p[2][i] + p[3][i]);
            }
#pragma unroll
            for (int st = 1; st <= 8; st <<= 1) {
#pragma unroll
                for (int i = 0; i < 4; i++) su[i] += __shfl_xor(su[i], st, 64);
            }
#pragma unroll
            for (int i = 0; i < 4; ++i) {
                l_r[i] += su[i];
#pragma unroll
                for (int tt = 0; tt < 4; ++tt)
                    Pw[(fq * 4 + i) * 72 + tt * 16 + fr] = f2bf(p[tt][i]);
            }

            // ---- PV: two kv-halves of 32, register-reusing vf ----
#pragma unroll
            for (int h2 = 0; h2 < 2; ++h2) {
                bf16x8 pa = *reinterpret_cast<const bf16x8*>(Pw + fr * 72 + h2 * 32 + fq * 8);
                bf16x8 vf[8];
#pragma unroll
                for (int f = 0; f < 8; ++f)
                    vf[f] = *reinterpret_cast<const bf16x8*>(
                        Vl + (f * 16 + fr) * 128 + ((h2 * 64 + fq * 16) ^ ((fr & 7) << 4)));
                __builtin_amdgcn_s_setprio(1);
#pragma unroll
                for (int f = 0; f < 8; ++f) acc[f] = MFMA(pa, vf[f], acc[f]);
                __builtin_amdgcn_s_setprio(0);
            }

            __syncthreads();
            cur ^= 1;
        }

        // epilogue: normalize (reciprocal-multiply) and store bf16 [4096][2048]
        float inv[4];
#pragma unroll
        for (int i = 0; i < 4; ++i) inv[i] = 1.0f / l_r[i];
#pragma unroll
        for (int f = 0; f < 8; f++) {
#pragma unroll
            for (int i = 0; i < 4; i++) {
                const int qrow = q0 + fq * 4 + i;
                const float o = acc[f][i] * inv[i];
                ao[(size_t)(b * 2048 + qrow) * 2048 + h * 128 + f * 16 + fr] = f2bf(o);
            }
        }
        // all waves passed the loop's final barrier; epilogue touches no LDS,
        // so seg1's stage(0,0) can safely overwrite buffers.
    }
}

// ---------------------------------------------------------------------------
extern "C" void kernel_launch(void* const* d_in, const int* in_sizes, int n_in,
                              void* d_out, int out_size, void* d_ws, size_t ws_size,
                              hipStream_t stream) {
    const float* x    = (const float*)d_in[0];
    const float* Wqkv = (const float*)d_in[1];
    const float* Wout = (const float*)d_in[2];
    float* out = (float*)d_out;

    // Workspace layout (96 MB), regions reused across phases:
    //   [0,16M):   xb (bf16 x), later reused as attnb
    //   [16M,40M): wqkvb (24M), later reused as vT (16M)
    //   [40M,48M): woutb
    //   [48M,96M): qkvb (bf16 [4096][6144])
    char* ws = (char*)d_ws;
    unsigned short* xb    = (unsigned short*)(ws);
    unsigned short* wqkvb = (unsigned short*)(ws + (size_t)(16 << 20));
    unsigned short* woutb = (unsigned short*)(ws + (size_t)(40 << 20));
    unsigned short* qkvb  = (unsigned short*)(ws + (size_t)(48 << 20));
    unsigned short* vTb   = (unsigned short*)(ws + (size_t)(16 << 20)); // over wqkvb
    unsigned short* attnb = (unsigned short*)(ws);                      // over xb

    cvt_f32_bf16<<<8192, 256, 0, stream>>>(x, xb, 2097152);
    cvt_f32_bf16<<<12288, 256, 0, stream>>>(Wqkv, wqkvb, 3145728);
    cvt_f32_bf16<<<4096, 256, 0, stream>>>(Wout, woutb, 1048576);

    // qkv = x @ W_qkv^T : M=4096, N=6144, K=2048, bf16 out
    gemm_bt<true><<<dim3(48, 32), 256, 0, stream>>>(xb, wqkvb, qkvb, 4096, 6144, 2048);

    // vT[b][h*128+dk][s] = V[b][s][h*128+dk]  (wqkvb dead after the GEMM)
    transpose_v<<<dim3(64, 64, 2), 256, 0, stream>>>(qkvb, vTb);

    // causal flash attention -> attnb (bf16 [4096][2048])  (xb dead now)
    attn_fwd<<<512, 256, 0, stream>>>(qkvb, vTb, attnb);

    // out = attnb @ W_out^T : M=4096, N=2048, K=2048, fp32 out
    gemm_bt<false><<<dim3(16, 32), 256, 0, stream>>>(attnb, woutb, out, 4096, 2048, 2048);
}